// Round 5
// baseline (1509.594 us; speedup 1.0000x reference)
//
#include <hip/hip_runtime.h>
#include <hip/hip_bf16.h>

typedef unsigned short u16;
typedef __attribute__((ext_vector_type(8))) short bf16x8;
typedef __attribute__((ext_vector_type(4))) float f32x4;
typedef __attribute__((ext_vector_type(4))) float vfloat4;
typedef __attribute__((ext_vector_type(4))) unsigned short ushort4v;
typedef __attribute__((ext_vector_type(8))) unsigned short ushort8v;

#define DEV __device__ __forceinline__
#define AS1 __attribute__((address_space(1)))
#define AS3 __attribute__((address_space(3)))

#define BARRIER()  __builtin_amdgcn_s_barrier()
#define LGKM0()    asm volatile("s_waitcnt lgkmcnt(0)" ::: "memory")
#define VMCNT6()   asm volatile("s_waitcnt vmcnt(6)" ::: "memory")
#define VMCNT4()   asm volatile("s_waitcnt vmcnt(4)" ::: "memory")
#define VMCNT8()   asm volatile("s_waitcnt vmcnt(8)" ::: "memory")
#define SCHED0()   __builtin_amdgcn_sched_barrier(0)

DEV u16 f2bf(float f) {
    union { float f; unsigned u; } v; v.f = f;
    unsigned r = v.u + 0x7FFFu + ((v.u >> 16) & 1u);
    return (u16)(r >> 16);
}

DEV void gload_lds16(const void* g, void* l) {
    __builtin_amdgcn_global_load_lds((const AS1 unsigned int*)g,
                                     (AS3 unsigned int*)l, 16, 0, 0);
}

static constexpr int KDIM = 1024;   // embed
static constexpr int NROW = 65536;  // B*S

// ---------------- fp32 -> bf16 convert (for the small W matrices) -----------
__global__ __launch_bounds__(256)
void cvt_f32_bf16(const float* __restrict__ src, u16* __restrict__ dst, unsigned n8)
{
    unsigned stride = gridDim.x * blockDim.x;
    for (unsigned i = blockIdx.x * blockDim.x + threadIdx.x; i < n8; i += stride) {
        size_t base = (size_t)i * 8;
        vfloat4 a = *(const vfloat4*)(src + base);
        vfloat4 b = *(const vfloat4*)(src + base + 4);
        ushort8v o;
#pragma unroll
        for (int j = 0; j < 4; ++j) { o[j] = f2bf(a[j]); o[j + 4] = f2bf(b[j]); }
        *(ushort8v*)(dst + base) = o;
    }
}

// ---------------- 8-phase fused projection GEMM -----------------------------
// Y = f2bf(X) @ Wb^T + b. 256x256 tile, BK=64, 16 K-tiles, 8 waves (2Mx4N),
// per-wave C 128x64 (acc[8][4]). Per K-tile: 4 phases, each
// {ds_read subtile | stage one half-tile} barrier lgkm0 prio 16xMFMA prio0 barrier.
// Counted vmcnt only (6 at p3, 4 at p4) -- loads stay in flight across barriers.
// A (fp32): reg-stage issue-early / cvt+ds_write-late. B (bf16): global_load_lds
// with pre-swizzled source (rule #21). LDS XOR swizzle ((row&7)<<4), stride 128B.
__global__ __launch_bounds__(512)
void proj_gemm_8ph(const float* __restrict__ X, const u16* __restrict__ W,
                   const float* __restrict__ bias, u16* __restrict__ Y)
{
    __shared__ __align__(16) u16 As[2][256 * 64];
    __shared__ __align__(16) u16 Bs[2][256 * 64];

    int bx = blockIdx.x;                  // 0..1023
    int wg = (bx & 7) * 128 + (bx >> 3);  // XCD-chunked swizzle (1024 % 8 == 0)
    int bm = wg >> 2;                     // 0..255
    int bn = wg & 3;                      // 0..3

    int tid  = threadIdx.x;
    int lane = tid & 63;
    int wid  = tid >> 6;       // 0..7
    int wm   = wid >> 2;       // 0..1
    int wn   = wid & 3;        // 0..3
    int l15  = lane & 15;
    int l4   = lane >> 4;

    const float* Xp = X + (size_t)bm * 256 * KDIM;
    const u16*   Wp = W + (size_t)bn * 256 * KDIM;

    // B staging: round j covers rows j*64+(tid>>3); source col16 pre-swizzled.
    int brow_in = tid >> 3;                       // 0..63
    int bcol16s = (tid & 7) ^ (brow_in & 7);      // involution with read XOR
    // A staging: thread covers (row_in = tid>>2, 2 slots of 16B = 16 floats)
    int arow_in = tid >> 2;                       // 0..127
    int aslot0  = (tid & 3) * 2;                  // 0,2,4,6

    f32x4 acc[8][4] = {};

#define GLOAD_B(slot, h, kt)                                                     \
    {                                                                            \
        const u16* wsrc = Wp + (kt) * 64 + bcol16s * 8;                          \
        gload_lds16(wsrc + (size_t)(((h) * 2) * 64 + brow_in) * KDIM,            \
                    &Bs[slot][(((h) * 2) * 64 + wid * 8) * 64]);                 \
        gload_lds16(wsrc + (size_t)(((h) * 2 + 1) * 64 + brow_in) * KDIM,        \
                    &Bs[slot][(((h) * 2 + 1) * 64 + wid * 8) * 64]);             \
    }

#define LOAD_A(dst, h, kt)                                                       \
    {                                                                            \
        const float* ga = Xp + (size_t)((h) * 128 + arow_in) * KDIM + (kt) * 64  \
                          + aslot0 * 8;                                          \
        dst[0] = *(const vfloat4*)ga;       dst[1] = *(const vfloat4*)(ga + 4);  \
        dst[2] = *(const vfloat4*)(ga + 8); dst[3] = *(const vfloat4*)(ga + 12); \
    }

#define WRITE_A(slot, h, srcv)                                                   \
    {                                                                            \
        int row = (h) * 128 + arow_in;                                           \
        ushort8v o0, o1;                                                         \
        for (int j = 0; j < 4; ++j) {                                            \
            o0[j] = f2bf(srcv[0][j]); o0[j + 4] = f2bf(srcv[1][j]);              \
            o1[j] = f2bf(srcv[2][j]); o1[j + 4] = f2bf(srcv[3][j]);              \
        }                                                                        \
        unsigned ob = (unsigned)(row * 128 + aslot0 * 16) ^ (unsigned)((arow_in & 7) << 4); \
        unsigned ob2 = (unsigned)(row * 128 + (aslot0 + 1) * 16) ^ (unsigned)((arow_in & 7) << 4); \
        *(ushort8v*)((char*)As[slot] + ob)  = o0;                                \
        *(ushort8v*)((char*)As[slot] + ob2) = o1;                                \
    }

#define READ_AF(slot, mh)                                                        \
    {                                                                            \
        for (int mi = 0; mi < 4; ++mi) {                                         \
            int row = wm * 128 + (mh) * 64 + mi * 16 + l15;                      \
            unsigned o0 = (unsigned)(row * 128 + l4 * 16) ^ (unsigned)((row & 7) << 4); \
            af[mi][0] = *(const bf16x8*)((const char*)As[slot] + o0);            \
            af[mi][1] = *(const bf16x8*)((const char*)As[slot] + (o0 ^ 64u));    \
        }                                                                        \
    }
    // note: (row*128 + kk*64 + l4*16): kk toggles bit6; XOR uses bit4 only, so
    // kk*64 can be applied as ^64 after the row-XOR.

#define READ_BF(dst, slot, nlo)                                                  \
    {                                                                            \
        for (int ni = 0; ni < 2; ++ni) {                                         \
            int row = wn * 64 + ((nlo) + ni) * 16 + l15;                         \
            unsigned o0 = (unsigned)(row * 128 + l4 * 16) ^ (unsigned)((row & 7) << 4); \
            dst[ni][0] = *(const bf16x8*)((const char*)Bs[slot] + o0);           \
            dst[ni][1] = *(const bf16x8*)((const char*)Bs[slot] + (o0 ^ 64u));   \
        }                                                                        \
    }

#define MFMA_Q(mlo, bfr, nlo)                                                    \
    __builtin_amdgcn_s_setprio(1);                                               \
    for (int mi = 0; mi < 4; ++mi)                                               \
        for (int ni = 0; ni < 2; ++ni)                                           \
            for (int kk = 0; kk < 2; ++kk)                                       \
                acc[(mlo) + mi][(nlo) + ni] = __builtin_amdgcn_mfma_f32_16x16x32_bf16( \
                    af[mi][kk], bfr[ni][kk], acc[(mlo) + mi][(nlo) + ni], 0, 0, 0); \
    __builtin_amdgcn_s_setprio(0);

    // ---- prologue: A(0)h0,h1 + A(1)h0 reg-loads; B(0),B(1) gloads
    {
        vfloat4 pa0[4], pa1[4], pa2[4];
        LOAD_A(pa0, 0, 0);
        LOAD_A(pa1, 1, 0);
        LOAD_A(pa2, 0, 1);
        GLOAD_B(0, 0, 0);
        GLOAD_B(0, 1, 0);
        GLOAD_B(1, 0, 1);
        GLOAD_B(1, 1, 1);
        VMCNT8();                 // 12 A-loads done; 8 B-gloads in flight
        WRITE_A(0, 0, pa0);
        WRITE_A(0, 1, pa1);
        WRITE_A(1, 0, pa2);
        VMCNT4();                 // B(0) landed; B(1)'s 4 in flight
        LGKM0();                  // ds_writes drained
        BARRIER();
    }

    // ---- main loop: 16 K-tiles, 4 phases each, unroll 2 so slot is literal
#pragma unroll 2
    for (int kt = 0; kt < 16; ++kt) {
        int s = kt & 1;
        int kt1 = (kt + 1 < 16) ? kt + 1 : 15;   // clamped sources keep vmcnt static
        int kt2 = (kt + 2 < 16) ? kt + 2 : 15;
        bf16x8 af[4][2], b0[2][2], b1[2][2];
        vfloat4 a1reg[4], a0reg[4];

        // -- phase 1: ds_read A-lo + B-lo; issue A(kt+1)h1 loads; MFMA Q(0,0)
        READ_AF(s, 0);
        READ_BF(b0, s, 0);
        LOAD_A(a1reg, 1, kt1);                    // outstanding: 4B + 4A = 8
        BARRIER(); LGKM0(); SCHED0();
        MFMA_Q(0, b0, 0);
        BARRIER();

        // -- phase 2: ds_read B-hi; issue A(kt+2)h0 loads; MFMA Q(0,2)
        READ_BF(b1, s, 2);
        LOAD_A(a0reg, 0, kt2);                    // outstanding: 12
        BARRIER(); LGKM0(); SCHED0();
        MFMA_Q(0, b1, 2);
        BARRIER();

        // -- phase 3: ds_read A-hi; gload B(kt+2)h0; drain a1; write A[s^1]h1
        READ_AF(s, 1);
        GLOAD_B(s, 0, kt2);                       // outstanding: 14
        VMCNT6();                                 // a1reg ready (newest 6 = a0 + bh0)
        WRITE_A(s ^ 1, 1, a1reg);
        BARRIER(); LGKM0(); SCHED0();
        MFMA_Q(4, b1, 2);
        BARRIER();

        // -- phase 4: gload B(kt+2)h1; drain a0; write A[s]h0; MFMA Q(4,0)
        GLOAD_B(s, 1, kt2);                       // outstanding: 8
        VMCNT4();                                 // a0reg ready (newest 4 = bh0+bh1)
        WRITE_A(s, 0, a0reg);
        BARRIER(); LGKM0(); SCHED0();
        MFMA_Q(4, b0, 0);
        BARRIER();
        // exit: outstanding 4 = B(kt+2) halves, landed before their group
    }

    // ---- epilogue: + bias, bf16 store. D-frag: col(N)=l15, rows(M)=l4*4+r
#pragma unroll
    for (int ni = 0; ni < 4; ++ni) {
        int col = bn * 256 + wn * 64 + ni * 16 + l15;
        float bv = bias[col];
#pragma unroll
        for (int mi = 0; mi < 8; ++mi) {
            int row0 = bm * 256 + wm * 128 + mi * 16 + l4 * 4;
#pragma unroll
            for (int r = 0; r < 4; ++r)
                Y[(size_t)(row0 + r) * KDIM + col] = f2bf(acc[mi][ni][r] + bv);
        }
    }
#undef GLOAD_B
#undef LOAD_A
#undef WRITE_A
#undef READ_AF
#undef READ_BF
#undef MFMA_Q
}

// ---------------- Fallback: fp32 in, convert in-loop (128^2, 2-barrier) -----
__global__ __launch_bounds__(256)
void proj_gemm(const float* __restrict__ X, const float* __restrict__ W,
               const float* __restrict__ bias, u16* __restrict__ Y)
{
    __shared__ u16 As[128 * 64];
    __shared__ u16 Bs[128 * 64];

    int bx = blockIdx.x;
    int wg = (bx & 7) * 512 + (bx >> 3);
    int bm = wg >> 3;
    int bn = wg & 7;

    int tid  = threadIdx.x;
    int lane = tid & 63;
    int wid  = tid >> 6;
    int wrow = (wid >> 1) * 64;
    int wcol = (wid & 1) * 64;
    int l15 = lane & 15;
    int l4  = lane >> 4;

    int srow = tid >> 4;
    int scol = (tid & 15) * 4;

    const float* Xp = X + (size_t)bm * 128 * KDIM;
    const float* Wp = W + (size_t)bn * 128 * KDIM;

    f32x4 acc[4][4] = {};

    for (int k0 = 0; k0 < KDIM; k0 += 64) {
        __syncthreads();
#pragma unroll
        for (int r = 0; r < 8; ++r) {
            int row = r * 16 + srow;
            vfloat4 a = *(const vfloat4*)(Xp + (size_t)row * KDIM + k0 + scol);
            vfloat4 b = *(const vfloat4*)(Wp + (size_t)row * KDIM + k0 + scol);
            ushort4v ap, bp;
#pragma unroll
            for (int j = 0; j < 4; ++j) { ap[j] = f2bf(a[j]); bp[j] = f2bf(b[j]); }
            unsigned off = (unsigned)(row * 128 + scol * 2) ^ (unsigned)((row & 7) << 4);
            *(ushort4v*)((char*)As + off) = ap;
            *(ushort4v*)((char*)Bs + off) = bp;
        }
        __syncthreads();
#pragma unroll
        for (int kk = 0; kk < 2; ++kk) {
            bf16x8 af[4], bfr[4];
#pragma unroll
            for (int mi = 0; mi < 4; ++mi) {
                int row = wrow + mi * 16 + l15;
                unsigned off = (unsigned)(row * 128 + kk * 64 + l4 * 16) ^ (unsigned)((row & 7) << 4);
                af[mi] = *(const bf16x8*)((char*)As + off);
            }
#pragma unroll
            for (int ni = 0; ni < 4; ++ni) {
                int row = wcol + ni * 16 + l15;
                unsigned off = (unsigned)(row * 128 + kk * 64 + l4 * 16) ^ (unsigned)((row & 7) << 4);
                bfr[ni] = *(const bf16x8*)((char*)Bs + off);
            }
#pragma unroll
            for (int mi = 0; mi < 4; ++mi)
#pragma unroll
                for (int ni = 0; ni < 4; ++ni)
                    acc[mi][ni] = __builtin_amdgcn_mfma_f32_16x16x32_bf16(
                        af[mi], bfr[ni], acc[mi][ni], 0, 0, 0);
        }
    }

#pragma unroll
    for (int ni = 0; ni < 4; ++ni) {
        int col = bn * 128 + wcol + ni * 16 + l15;
        float bv = bias[col];
#pragma unroll
        for (int mi = 0; mi < 4; ++mi) {
            int row0 = bm * 128 + wrow + mi * 16 + l4 * 4;
#pragma unroll
            for (int r = 0; r < 4; ++r)
                Y[(size_t)(row0 + r) * KDIM + col] = f2bf(acc[mi][ni][r] + bv);
        }
    }
}

// ---------------- Pass 2: grouped attention ----------------
__global__ __launch_bounds__(256)
void attn_kernel(const u16* __restrict__ Qg, const u16* __restrict__ Kg,
                 const u16* __restrict__ Vg, float* __restrict__ Out)
{
    __shared__ u16 Qs[128 * 64];     // [q][d] swizzled
    __shared__ u16 KVs[64 * 136];    // union: Ks [128][64] swizzled / Vt [64][136]
    __shared__ u16 Ps[128 * 136];    // [q][k], row stride 136

    int g = blockIdx.x >> 4;
    int h = blockIdx.x & 15;

    int tid  = threadIdx.x;
    int lane = tid & 63;
    int wid  = tid >> 6;
    int l15 = lane & 15, l4 = lane >> 4;
    int qbase = wid * 32;

    size_t rowbase = (size_t)g * 128 * 1024 + (size_t)h * 64;

    {
        int r  = tid >> 1;
        int c0 = (tid & 1) * 32;
        const u16* qsrc = Qg + rowbase + (size_t)r * 1024 + c0;
        const u16* ksrc = Kg + rowbase + (size_t)r * 1024 + c0;
#pragma unroll
        for (int i = 0; i < 4; ++i) {
            ushort8v qv = *(const ushort8v*)(qsrc + i * 8);
            ushort8v kv = *(const ushort8v*)(ksrc + i * 8);
            unsigned off = (unsigned)(r * 128 + (c0 + i * 8) * 2) ^ (unsigned)((r & 7) << 4);
            *(ushort8v*)((char*)Qs + off) = qv;
            *(ushort8v*)((char*)KVs + off) = kv;
        }
    }
    __syncthreads();

    f32x4 st[8][2] = {};
#pragma unroll
    for (int kk = 0; kk < 2; ++kk) {
        bf16x8 kf[8];
#pragma unroll
        for (int mi = 0; mi < 8; ++mi) {
            int row = mi * 16 + l15;
            unsigned off = (unsigned)(row * 128 + kk * 64 + l4 * 16) ^ (unsigned)((row & 7) << 4);
            kf[mi] = *(const bf16x8*)((char*)KVs + off);
        }
#pragma unroll
        for (int qi = 0; qi < 2; ++qi) {
            int row = qbase + qi * 16 + l15;
            unsigned off = (unsigned)(row * 128 + kk * 64 + l4 * 16) ^ (unsigned)((row & 7) << 4);
            bf16x8 qf = *(const bf16x8*)((char*)Qs + off);
#pragma unroll
            for (int mi = 0; mi < 8; ++mi)
                st[mi][qi] = __builtin_amdgcn_mfma_f32_16x16x32_bf16(kf[mi], qf, st[mi][qi], 0, 0, 0);
        }
    }
    __syncthreads();

    {
        int r  = tid >> 1;
        int c0 = (tid & 1) * 32;
        const u16* vsrc = Vg + rowbase + (size_t)r * 1024 + c0;
#pragma unroll
        for (int i = 0; i < 4; ++i) {
            ushort8v vv = *(const ushort8v*)(vsrc + i * 8);
#pragma unroll
            for (int e = 0; e < 8; ++e)
                KVs[(c0 + i * 8 + e) * 136 + r] = vv[e];
        }
    }

    const float cexp = 0.125f * 1.44269504088896f;
#pragma unroll
    for (int qi = 0; qi < 2; ++qi) {
        float m = -3.0e38f;
#pragma unroll
        for (int mi = 0; mi < 8; ++mi)
#pragma unroll
            for (int r = 0; r < 4; ++r) m = fmaxf(m, st[mi][qi][r]);
        m = fmaxf(m, __shfl_xor(m, 16));
        m = fmaxf(m, __shfl_xor(m, 32));
        float s = 0.f;
#pragma unroll
        for (int mi = 0; mi < 8; ++mi)
#pragma unroll
            for (int r = 0; r < 4; ++r) {
                float p = exp2f((st[mi][qi][r] - m) * cexp);
                st[mi][qi][r] = p;
                s += p;
            }
        s += __shfl_xor(s, 16);
        s += __shfl_xor(s, 32);
        float inv = 1.0f / s;
        int q = qbase + qi * 16 + l15;
#pragma unroll
        for (int mi = 0; mi < 8; ++mi) {
            ushort4v pp;
#pragma unroll
            for (int r = 0; r < 4; ++r) pp[r] = f2bf(st[mi][qi][r] * inv);
            *(ushort4v*)((char*)Ps + (unsigned)(q * 272 + mi * 32 + l4 * 8)) = pp;
        }
    }
    __syncthreads();

    f32x4 o[2][4] = {};
#pragma unroll
    for (int kk = 0; kk < 4; ++kk) {
        bf16x8 pa[2];
#pragma unroll
        for (int mf = 0; mf < 2; ++mf) {
            int q = qbase + mf * 16 + l15;
            pa[mf] = *(const bf16x8*)((char*)Ps + (unsigned)(q * 272 + kk * 64 + l4 * 16));
        }
#pragma unroll
        for (int nf = 0; nf < 4; ++nf) {
            int d = nf * 16 + l15;
            bf16x8 vb = *(const bf16x8*)((char*)KVs + (unsigned)(d * 272 + kk * 64 + l4 * 16));
#pragma unroll
            for (int mf = 0; mf < 2; ++mf)
                o[mf][nf] = __builtin_amdgcn_mfma_f32_16x16x32_bf16(pa[mf], vb, o[mf][nf], 0, 0, 0);
        }
    }

#pragma unroll
    for (int mf = 0; mf < 2; ++mf)
#pragma unroll
        for (int nf = 0; nf < 4; ++nf) {
            int d  = nf * 16 + l15;
            int q0 = qbase + mf * 16 + l4 * 4;
#pragma unroll
            for (int r = 0; r < 4; ++r)
                Out[(size_t)(g * 128 + q0 + r) * 1024 + h * 64 + d] = o[mf][nf][r];
        }
}

extern "C" void kernel_launch(void* const* d_in, const int* in_sizes, int n_in,
                              void* d_out, int out_size, void* d_ws, size_t ws_size,
                              hipStream_t stream)
{
    const float* Xq = (const float*)d_in[0];
    const float* Xk = (const float*)d_in[1];
    const float* Xv = (const float*)d_in[2];
    const float* Wq = (const float*)d_in[3];
    const float* bq = (const float*)d_in[4];
    const float* Wk = (const float*)d_in[5];
    const float* bk = (const float*)d_in[6];
    const float* Wv = (const float*)d_in[7];
    const float* bv = (const float*)d_in[8];

    const size_t NE = (size_t)NROW * KDIM;       // 67,108,864
    const size_t WE = (size_t)KDIM * KDIM;       // 1,048,576

    u16* Qw = (u16*)d_ws;
    u16* Kw = Qw + NE;
    u16* Vw = Kw + NE;

    size_t need = NE * 2 * 3 + WE * 2 * 3;       // QKV bf16 + 3 W bf16

    if (ws_size >= need) {
        u16* Wb0 = Vw + NE;
        u16* Wb1 = Wb0 + WE;
        u16* Wb2 = Wb1 + WE;

        cvt_f32_bf16<<<dim3(512), dim3(256), 0, stream>>>(Wq, Wb0, (unsigned)(WE / 8));
        cvt_f32_bf16<<<dim3(512), dim3(256), 0, stream>>>(Wk, Wb1, (unsigned)(WE / 8));
        cvt_f32_bf16<<<dim3(512), dim3(256), 0, stream>>>(Wv, Wb2, (unsigned)(WE / 8));

        proj_gemm_8ph<<<dim3(1024), dim3(512), 0, stream>>>(Xq, Wb0, bq, Qw);
        proj_gemm_8ph<<<dim3(1024), dim3(512), 0, stream>>>(Xk, Wb1, bk, Kw);
        proj_gemm_8ph<<<dim3(1024), dim3(512), 0, stream>>>(Xv, Wb2, bv, Vw);
    } else {
        proj_gemm<<<dim3(4096), dim3(256), 0, stream>>>(Xq, Wq, bq, Qw);
        proj_gemm<<<dim3(4096), dim3(256), 0, stream>>>(Xk, Wk, bk, Kw);
        proj_gemm<<<dim3(4096), dim3(256), 0, stream>>>(Xv, Wv, bv, Vw);
    }

    attn_kernel<<<dim3(512 * 16), dim3(256), 0, stream>>>(Qw, Kw, Vw, (float*)d_out);
}

// Round 6
// 927.618 us; speedup vs baseline: 1.6274x; 1.6274x over previous
//
#include <hip/hip_runtime.h>
#include <hip/hip_bf16.h>

typedef unsigned short u16;
typedef __attribute__((ext_vector_type(8))) short bf16x8;
typedef __attribute__((ext_vector_type(4))) float f32x4;
typedef __attribute__((ext_vector_type(4))) float vfloat4;
typedef __attribute__((ext_vector_type(4))) unsigned short ushort4v;
typedef __attribute__((ext_vector_type(8))) unsigned short ushort8v;

#define DEV __device__ __forceinline__
#define AS1 __attribute__((address_space(1)))
#define AS3 __attribute__((address_space(3)))

#define BARRIER()  __builtin_amdgcn_s_barrier()
#define LGKM0()    asm volatile("s_waitcnt lgkmcnt(0)" ::: "memory")
#define VMCNT2()   asm volatile("s_waitcnt vmcnt(2)" ::: "memory")
#define SCHED0()   __builtin_amdgcn_sched_barrier(0)

DEV u16 f2bf(float f) {
    union { float f; unsigned u; } v; v.f = f;
    unsigned r = v.u + 0x7FFFu + ((v.u >> 16) & 1u);
    return (u16)(r >> 16);
}

DEV void gload_lds16(const void* g, void* l) {
    __builtin_amdgcn_global_load_lds((const AS1 unsigned int*)g,
                                     (AS3 unsigned int*)l, 16, 0, 0);
}

static constexpr int KDIM = 1024;   // embed
static constexpr int NROW = 65536;  // B*S

// ---------------- fp32 -> bf16 convert (memory-bound) ----------------
__global__ __launch_bounds__(256)
void cvt_f32_bf16(const float* __restrict__ src, u16* __restrict__ dst, unsigned n8)
{
    unsigned stride = gridDim.x * blockDim.x;
    for (unsigned i = blockIdx.x * blockDim.x + threadIdx.x; i < n8; i += stride) {
        size_t base = (size_t)i * 8;
        vfloat4 a = *(const vfloat4*)(src + base);
        vfloat4 b = *(const vfloat4*)(src + base + 4);
        ushort8v o;
#pragma unroll
        for (int j = 0; j < 4; ++j) { o[j] = f2bf(a[j]); o[j + 4] = f2bf(b[j]); }
        *(ushort8v*)(dst + base) = o;
    }
}

// ---------------- 8-phase 256^2 bf16 GEMM (m201 port) ------------------------
// Y = Xb @ Wb^T + b. All bf16 in. BM=BN=256, BK=64, 16 K-tiles, 8 waves (2Mx4N),
// per-wave C 128x64 (acc[8][4] -> AGPRs). Both A,B staged via global_load_lds
// with pre-swizzled source (rule #21); fixed slot pairing (even K-tile -> slot0,
// odd -> slot1). 8 phases / 2 K-tiles; 2 gloads per phase; counted vmcnt(2)
// ONLY at end of P4 and P8, placed BEFORE the closing barrier so the barrier
// gives the cross-wave completion guarantee.
__global__ __launch_bounds__(512, 2)
void proj_gemm_8ph(const u16* __restrict__ X, const u16* __restrict__ W,
                   const float* __restrict__ bias, u16* __restrict__ Y)
{
    __shared__ __align__(16) u16 As[2][256 * 64];
    __shared__ __align__(16) u16 Bs[2][256 * 64];

    int bx = blockIdx.x;                  // 0..1023
    int wg = (bx & 7) * 128 + (bx >> 3);  // XCD-chunked swizzle (1024 % 8 == 0)
    int bm = wg >> 2;                     // 0..255
    int bn = wg & 3;                      // 0..3

    int tid  = threadIdx.x;
    int lane = tid & 63;
    int wid  = tid >> 6;       // 0..7
    int wm   = wid >> 2;       // 0..1
    int wn   = wid & 3;        // 0..3
    int l15  = lane & 15;
    int l4   = lane >> 4;

    const u16* Xp = X + (size_t)bm * 256 * KDIM;
    const u16* Wp = W + (size_t)bn * 256 * KDIM;

    // staging: lane covers (row_in = tid>>3 in 0..63, col16 = tid&7); the
    // global source col is XOR'd with row so linear LDS dest holds swizzled data
    int srow_in = tid >> 3;
    int scol16  = (tid & 7) ^ (srow_in & 7);

    f32x4 acc[8][4] = {};

    // one half-tile = 128 rows x 64 cols = 2 gload issues (64 rows each)
#define STAGE(lds, gbase, slot, h, kt)                                           \
    {                                                                            \
        const u16* src_ = (gbase) + (size_t)((h) * 128 + srow_in) * KDIM         \
                          + (kt) * 64 + scol16 * 8;                              \
        gload_lds16(src_, &lds[slot][((h) * 128 + wid * 8) * 64]);               \
        gload_lds16(src_ + (size_t)64 * KDIM,                                    \
                    &lds[slot][((h) * 128 + 64 + wid * 8) * 64]);                \
    }

#define READ_AF(slot, mh)                                                        \
    {                                                                            \
        for (int mi = 0; mi < 4; ++mi) {                                         \
            int row = wm * 128 + (mh) * 64 + mi * 16 + l15;                      \
            unsigned o0 = (unsigned)(row * 128 + l4 * 16) ^ (unsigned)((row & 7) << 4); \
            af[mi][0] = *(const bf16x8*)((const char*)As[slot] + o0);            \
            af[mi][1] = *(const bf16x8*)((const char*)As[slot] + (o0 ^ 64u));    \
        }                                                                        \
    }

#define READ_BF(dst, slot, nh)                                                   \
    {                                                                            \
        for (int ni = 0; ni < 2; ++ni) {                                         \
            int row = wn * 64 + (nh) * 32 + ni * 16 + l15;                       \
            unsigned o0 = (unsigned)(row * 128 + l4 * 16) ^ (unsigned)((row & 7) << 4); \
            dst[ni][0] = *(const bf16x8*)((const char*)Bs[slot] + o0);           \
            dst[ni][1] = *(const bf16x8*)((const char*)Bs[slot] + (o0 ^ 64u));   \
        }                                                                        \
    }

#define MFMA_Q(mlo, bb, nlo)                                                     \
    __builtin_amdgcn_s_setprio(1);                                               \
    for (int mi = 0; mi < 4; ++mi)                                               \
        for (int ni = 0; ni < 2; ++ni)                                           \
            for (int kk = 0; kk < 2; ++kk)                                       \
                acc[(mlo) + mi][(nlo) + ni] = __builtin_amdgcn_mfma_f32_16x16x32_bf16( \
                    af[mi][kk], bb[ni][kk], acc[(mlo) + mi][(nlo) + ni], 0, 0, 0); \
    __builtin_amdgcn_s_setprio(0);

    // ---- prologue: kt0 -> slot0 (8 gloads, oldest), A-lo(kt1) -> slot1 (2)
    STAGE(As, Xp, 0, 0, 0);
    STAGE(As, Xp, 0, 1, 0);
    STAGE(Bs, Wp, 0, 0, 0);
    STAGE(Bs, Wp, 0, 1, 0);
    STAGE(As, Xp, 1, 0, 1);
    VMCNT2();                 // kt0's 8 landed; slot1 A-lo may fly
    BARRIER();

    // ---- main loop: 8 iterations x 2 K-tiles
    for (int it = 0; it < 8; ++it) {
        int kt1 = 2 * it + 1;                       // slot1 content this iter
        int kt2 = (2 * it + 2 < 16) ? 2 * it + 2 : 15;  // next slot0 content
        int kt3 = (2 * it + 3 < 16) ? 2 * it + 3 : 15;  // next slot1 content
        bf16x8 af[4][2], b0[2][2], b1[2][2];

        // P1: read slot0 af-lo + b-lo; stage A-hi(kt1)->slot1
        READ_AF(0, 0); READ_BF(b0, 0, 0);
        STAGE(As, Xp, 1, 1, kt1);
        BARRIER(); LGKM0(); SCHED0();
        MFMA_Q(0, b0, 0);
        BARRIER();

        // P2: read b-hi; stage B-lo(kt1)->slot1
        READ_BF(b1, 0, 1);
        STAGE(Bs, Wp, 1, 0, kt1);
        BARRIER(); LGKM0(); SCHED0();
        MFMA_Q(0, b1, 2);
        BARRIER();

        // P3: read af-hi; stage B-hi(kt1)->slot1
        READ_AF(0, 1);
        STAGE(Bs, Wp, 1, 1, kt1);
        BARRIER(); LGKM0(); SCHED0();
        MFMA_Q(4, b1, 2);
        BARRIER();

        // P4: stage A-lo(kt2)->slot0 (slot0 A-lo last read P1); MFMA from regs;
        //     vmcnt(2) BEFORE closing barrier => slot1 (kt1) fully landed for P5
        STAGE(As, Xp, 0, 0, kt2);
        MFMA_Q(4, b0, 0);
        VMCNT2();
        BARRIER();

        // P5: read slot1 af-lo + b-lo; stage A-hi(kt2)->slot0
        READ_AF(1, 0); READ_BF(b0, 1, 0);
        STAGE(As, Xp, 0, 1, kt2);
        BARRIER(); LGKM0(); SCHED0();
        MFMA_Q(0, b0, 0);
        BARRIER();

        // P6: read b-hi; stage B-lo(kt2)->slot0
        READ_BF(b1, 1, 1);
        STAGE(Bs, Wp, 0, 0, kt2);
        BARRIER(); LGKM0(); SCHED0();
        MFMA_Q(0, b1, 2);
        BARRIER();

        // P7: read af-hi; stage B-hi(kt2)->slot0
        READ_AF(1, 1);
        STAGE(Bs, Wp, 0, 1, kt2);
        BARRIER(); LGKM0(); SCHED0();
        MFMA_Q(4, b1, 2);
        BARRIER();

        // P8: stage A-lo(kt3)->slot1 (slot1 A-lo last read P5); MFMA from regs;
        //     vmcnt(2) => slot0 (kt2) fully landed for next-iter P1
        STAGE(As, Xp, 1, 0, kt3);
        MFMA_Q(4, b0, 0);
        VMCNT2();
        BARRIER();
    }

    // ---- epilogue: + bias, bf16 store. D-frag: col(N)=l15, rows(M)=l4*4+r
#pragma unroll
    for (int ni = 0; ni < 4; ++ni) {
        int col = bn * 256 + wn * 64 + ni * 16 + l15;
        float bv = bias[col];
#pragma unroll
        for (int mi = 0; mi < 8; ++mi) {
            int row0 = bm * 256 + wm * 128 + mi * 16 + l4 * 4;
#pragma unroll
            for (int r = 0; r < 4; ++r)
                Y[(size_t)(row0 + r) * KDIM + col] = f2bf(acc[mi][ni][r] + bv);
        }
    }
#undef STAGE
#undef READ_AF
#undef READ_BF
#undef MFMA_Q
}

// ---------------- Fallback: fp32 in, convert in-loop (128^2, 2-barrier) -----
__global__ __launch_bounds__(256)
void proj_gemm(const float* __restrict__ X, const float* __restrict__ W,
               const float* __restrict__ bias, u16* __restrict__ Y)
{
    __shared__ u16 As[128 * 64];
    __shared__ u16 Bs[128 * 64];

    int bx = blockIdx.x;
    int wg = (bx & 7) * 512 + (bx >> 3);
    int bm = wg >> 3;
    int bn = wg & 7;

    int tid  = threadIdx.x;
    int lane = tid & 63;
    int wid  = tid >> 6;
    int wrow = (wid >> 1) * 64;
    int wcol = (wid & 1) * 64;
    int l15 = lane & 15;
    int l4  = lane >> 4;

    int srow = tid >> 4;
    int scol = (tid & 15) * 4;

    const float* Xp = X + (size_t)bm * 128 * KDIM;
    const float* Wp = W + (size_t)bn * 128 * KDIM;

    f32x4 acc[4][4] = {};

    for (int k0 = 0; k0 < KDIM; k0 += 64) {
        __syncthreads();
#pragma unroll
        for (int r = 0; r < 8; ++r) {
            int row = r * 16 + srow;
            vfloat4 a = *(const vfloat4*)(Xp + (size_t)row * KDIM + k0 + scol);
            vfloat4 b = *(const vfloat4*)(Wp + (size_t)row * KDIM + k0 + scol);
            ushort4v ap, bp;
#pragma unroll
            for (int j = 0; j < 4; ++j) { ap[j] = f2bf(a[j]); bp[j] = f2bf(b[j]); }
            unsigned off = (unsigned)(row * 128 + scol * 2) ^ (unsigned)((row & 7) << 4);
            *(ushort4v*)((char*)As + off) = ap;
            *(ushort4v*)((char*)Bs + off) = bp;
        }
        __syncthreads();
#pragma unroll
        for (int kk = 0; kk < 2; ++kk) {
            bf16x8 af[4], bfr[4];
#pragma unroll
            for (int mi = 0; mi < 4; ++mi) {
                int row = wrow + mi * 16 + l15;
                unsigned off = (unsigned)(row * 128 + kk * 64 + l4 * 16) ^ (unsigned)((row & 7) << 4);
                af[mi] = *(const bf16x8*)((char*)As + off);
            }
#pragma unroll
            for (int ni = 0; ni < 4; ++ni) {
                int row = wcol + ni * 16 + l15;
                unsigned off = (unsigned)(row * 128 + kk * 64 + l4 * 16) ^ (unsigned)((row & 7) << 4);
                bfr[ni] = *(const bf16x8*)((char*)Bs + off);
            }
#pragma unroll
            for (int mi = 0; mi < 4; ++mi)
#pragma unroll
                for (int ni = 0; ni < 4; ++ni)
                    acc[mi][ni] = __builtin_amdgcn_mfma_f32_16x16x32_bf16(
                        af[mi], bfr[ni], acc[mi][ni], 0, 0, 0);
        }
    }

#pragma unroll
    for (int ni = 0; ni < 4; ++ni) {
        int col = bn * 128 + wcol + ni * 16 + l15;
        float bv = bias[col];
#pragma unroll
        for (int mi = 0; mi < 4; ++mi) {
            int row0 = bm * 128 + wrow + mi * 16 + l4 * 4;
#pragma unroll
            for (int r = 0; r < 4; ++r)
                Y[(size_t)(row0 + r) * KDIM + col] = f2bf(acc[mi][ni][r] + bv);
        }
    }
}

// ---------------- Pass 2: grouped attention ----------------
__global__ __launch_bounds__(256)
void attn_kernel(const u16* __restrict__ Qg, const u16* __restrict__ Kg,
                 const u16* __restrict__ Vg, float* __restrict__ Out)
{
    __shared__ u16 Qs[128 * 64];     // [q][d] swizzled
    __shared__ u16 KVs[64 * 136];    // union: Ks [128][64] swizzled / Vt [64][136]
    __shared__ u16 Ps[128 * 136];    // [q][k], row stride 136

    int g = blockIdx.x >> 4;
    int h = blockIdx.x & 15;

    int tid  = threadIdx.x;
    int lane = tid & 63;
    int wid  = tid >> 6;
    int l15 = lane & 15, l4 = lane >> 4;
    int qbase = wid * 32;

    size_t rowbase = (size_t)g * 128 * 1024 + (size_t)h * 64;

    {
        int r  = tid >> 1;
        int c0 = (tid & 1) * 32;
        const u16* qsrc = Qg + rowbase + (size_t)r * 1024 + c0;
        const u16* ksrc = Kg + rowbase + (size_t)r * 1024 + c0;
#pragma unroll
        for (int i = 0; i < 4; ++i) {
            ushort8v qv = *(const ushort8v*)(qsrc + i * 8);
            ushort8v kv = *(const ushort8v*)(ksrc + i * 8);
            unsigned off = (unsigned)(r * 128 + (c0 + i * 8) * 2) ^ (unsigned)((r & 7) << 4);
            *(ushort8v*)((char*)Qs + off) = qv;
            *(ushort8v*)((char*)KVs + off) = kv;
        }
    }
    __syncthreads();

    f32x4 st[8][2] = {};
#pragma unroll
    for (int kk = 0; kk < 2; ++kk) {
        bf16x8 kf[8];
#pragma unroll
        for (int mi = 0; mi < 8; ++mi) {
            int row = mi * 16 + l15;
            unsigned off = (unsigned)(row * 128 + kk * 64 + l4 * 16) ^ (unsigned)((row & 7) << 4);
            kf[mi] = *(const bf16x8*)((char*)KVs + off);
        }
#pragma unroll
        for (int qi = 0; qi < 2; ++qi) {
            int row = qbase + qi * 16 + l15;
            unsigned off = (unsigned)(row * 128 + kk * 64 + l4 * 16) ^ (unsigned)((row & 7) << 4);
            bf16x8 qf = *(const bf16x8*)((char*)Qs + off);
#pragma unroll
            for (int mi = 0; mi < 8; ++mi)
                st[mi][qi] = __builtin_amdgcn_mfma_f32_16x16x32_bf16(kf[mi], qf, st[mi][qi], 0, 0, 0);
        }
    }
    __syncthreads();

    {
        int r  = tid >> 1;
        int c0 = (tid & 1) * 32;
        const u16* vsrc = Vg + rowbase + (size_t)r * 1024 + c0;
#pragma unroll
        for (int i = 0; i < 4; ++i) {
            ushort8v vv = *(const ushort8v*)(vsrc + i * 8);
#pragma unroll
            for (int e = 0; e < 8; ++e)
                KVs[(c0 + i * 8 + e) * 136 + r] = vv[e];
        }
    }

    const float cexp = 0.125f * 1.44269504088896f;
#pragma unroll
    for (int qi = 0; qi < 2; ++qi) {
        float m = -3.0e38f;
#pragma unroll
        for (int mi = 0; mi < 8; ++mi)
#pragma unroll
            for (int r = 0; r < 4; ++r) m = fmaxf(m, st[mi][qi][r]);
        m = fmaxf(m, __shfl_xor(m, 16));
        m = fmaxf(m, __shfl_xor(m, 32));
        float s = 0.f;
#pragma unroll
        for (int mi = 0; mi < 8; ++mi)
#pragma unroll
            for (int r = 0; r < 4; ++r) {
                float p = exp2f((st[mi][qi][r] - m) * cexp);
                st[mi][qi][r] = p;
                s += p;
            }
        s += __shfl_xor(s, 16);
        s += __shfl_xor(s, 32);
        float inv = 1.0f / s;
        int q = qbase + qi * 16 + l15;
#pragma unroll
        for (int mi = 0; mi < 8; ++mi) {
            ushort4v pp;
#pragma unroll
            for (int r = 0; r < 4; ++r) pp[r] = f2bf(st[mi][qi][r] * inv);
            *(ushort4v*)((char*)Ps + (unsigned)(q * 272 + mi * 32 + l4 * 8)) = pp;
        }
    }
    __syncthreads();

    f32x4 o[2][4] = {};
#pragma unroll
    for (int kk = 0; kk < 4; ++kk) {
        bf16x8 pa[2];
#pragma unroll
        for (int mf = 0; mf < 2; ++mf) {
            int q = qbase + mf * 16 + l15;
            pa[mf] = *(const bf16x8*)((char*)Ps + (unsigned)(q * 272 + kk * 64 + l4 * 16));
        }
#pragma unroll
        for (int nf = 0; nf < 4; ++nf) {
            int d = nf * 16 + l15;
            bf16x8 vb = *(const bf16x8*)((char*)KVs + (unsigned)(d * 272 + kk * 64 + l4 * 16));
#pragma unroll
            for (int mf = 0; mf < 2; ++mf)
                o[mf][nf] = __builtin_amdgcn_mfma_f32_16x16x32_bf16(pa[mf], vb, o[mf][nf], 0, 0, 0);
        }
    }

#pragma unroll
    for (int mf = 0; mf < 2; ++mf)
#pragma unroll
        for (int nf = 0; nf < 4; ++nf) {
            int d  = nf * 16 + l15;
            int q0 = qbase + mf * 16 + l4 * 4;
#pragma unroll
            for (int r = 0; r < 4; ++r)
                Out[(size_t)(g * 128 + q0 + r) * 1024 + h * 64 + d] = o[mf][nf][r];
        }
}

extern "C" void kernel_launch(void* const* d_in, const int* in_sizes, int n_in,
                              void* d_out, int out_size, void* d_ws, size_t ws_size,
                              hipStream_t stream)
{
    const float* Xq = (const float*)d_in[0];
    const float* Xk = (const float*)d_in[1];
    const float* Xv = (const float*)d_in[2];
    const float* Wq = (const float*)d_in[3];
    const float* bq = (const float*)d_in[4];
    const float* Wk = (const float*)d_in[5];
    const float* bk = (const float*)d_in[6];
    const float* Wv = (const float*)d_in[7];
    const float* bv = (const float*)d_in[8];

    const size_t NE = (size_t)NROW * KDIM;       // 67,108,864
    const size_t WE = (size_t)KDIM * KDIM;       // 1,048,576

    u16* Qw = (u16*)d_ws;
    u16* Kw = Qw + NE;
    u16* Vw = Kw + NE;

    size_t need = NE * 2 * 3 + NE * 2 + WE * 2 * 3;  // QKV + X-stage + 3 W

    if (ws_size >= need) {
        u16* Xb  = Vw + NE;          // shared X staging buffer (reused 3x)
        u16* Wb0 = Xb + NE;
        u16* Wb1 = Wb0 + WE;
        u16* Wb2 = Wb1 + WE;

        cvt_f32_bf16<<<dim3(512),  dim3(256), 0, stream>>>(Wq, Wb0, (unsigned)(WE / 8));
        cvt_f32_bf16<<<dim3(512),  dim3(256), 0, stream>>>(Wk, Wb1, (unsigned)(WE / 8));
        cvt_f32_bf16<<<dim3(512),  dim3(256), 0, stream>>>(Wv, Wb2, (unsigned)(WE / 8));

        cvt_f32_bf16<<<dim3(2048), dim3(256), 0, stream>>>(Xq, Xb, (unsigned)(NE / 8));
        proj_gemm_8ph<<<dim3(1024), dim3(512), 0, stream>>>(Xb, Wb0, bq, Qw);
        cvt_f32_bf16<<<dim3(2048), dim3(256), 0, stream>>>(Xk, Xb, (unsigned)(NE / 8));
        proj_gemm_8ph<<<dim3(1024), dim3(512), 0, stream>>>(Xb, Wb1, bk, Kw);
        cvt_f32_bf16<<<dim3(2048), dim3(256), 0, stream>>>(Xv, Xb, (unsigned)(NE / 8));
        proj_gemm_8ph<<<dim3(1024), dim3(512), 0, stream>>>(Xb, Wb2, bv, Vw);
    } else {
        proj_gemm<<<dim3(4096), dim3(256), 0, stream>>>(Xq, Wq, bq, Qw);
        proj_gemm<<<dim3(4096), dim3(256), 0, stream>>>(Xk, Wk, bk, Kw);
        proj_gemm<<<dim3(4096), dim3(256), 0, stream>>>(Xv, Wv, bv, Vw);
    }

    attn_kernel<<<dim3(512 * 16), dim3(256), 0, stream>>>(Qw, Kw, Vw, (float*)d_out);
}

// Round 7
// 927.292 us; speedup vs baseline: 1.6280x; 1.0004x over previous
//
#include <hip/hip_runtime.h>
#include <hip/hip_bf16.h>

typedef unsigned short u16;
typedef __attribute__((ext_vector_type(8))) short bf16x8;
typedef __attribute__((ext_vector_type(4))) float f32x4;
typedef __attribute__((ext_vector_type(4))) float vfloat4;
typedef __attribute__((ext_vector_type(4))) unsigned short ushort4v;
typedef __attribute__((ext_vector_type(8))) unsigned short ushort8v;

#define DEV __device__ __forceinline__
#define AS1 __attribute__((address_space(1)))
#define AS3 __attribute__((address_space(3)))

#define BARRIER()  __builtin_amdgcn_s_barrier()
#define LGKM0()    asm volatile("s_waitcnt lgkmcnt(0)" ::: "memory")
#define VMCNT2()   asm volatile("s_waitcnt vmcnt(2)" ::: "memory")
#define SCHED0()   __builtin_amdgcn_sched_barrier(0)

DEV u16 f2bf(float f) {
    union { float f; unsigned u; } v; v.f = f;
    unsigned r = v.u + 0x7FFFu + ((v.u >> 16) & 1u);
    return (u16)(r >> 16);
}

DEV void gload_lds16(const void* g, void* l) {
    __builtin_amdgcn_global_load_lds((const AS1 unsigned int*)g,
                                     (AS3 unsigned int*)l, 16, 0, 0);
}

static constexpr int KDIM = 1024;   // embed
static constexpr int NROW = 65536;  // B*S

// ---------------- fp32 -> bf16 convert (memory-bound) ----------------
__global__ __launch_bounds__(256)
void cvt_f32_bf16(const float* __restrict__ src, u16* __restrict__ dst, unsigned n8)
{
    unsigned stride = gridDim.x * blockDim.x;
    for (unsigned i = blockIdx.x * blockDim.x + threadIdx.x; i < n8; i += stride) {
        size_t base = (size_t)i * 8;
        vfloat4 a = *(const vfloat4*)(src + base);
        vfloat4 b = *(const vfloat4*)(src + base + 4);
        ushort8v o;
#pragma unroll
        for (int j = 0; j < 4; ++j) { o[j] = f2bf(a[j]); o[j + 4] = f2bf(b[j]); }
        *(ushort8v*)(dst + base) = o;
    }
}

// ---------------- 8-phase 256^2 bf16 GEMM (m201 port) ------------------------
// Y = Xb @ Wb^T + b. All bf16 in. BM=BN=256, BK=64, 16 K-tiles, 8 waves (2Mx4N),
// per-wave C 128x64 (acc[8][4]). Both A,B staged via global_load_lds with
// pre-swizzled source (rule #21); fixed slot pairing. 8 phases / 2 K-tiles;
// counted vmcnt(2) only at P4/P8 before the closing barrier.
// __launch_bounds__(512, 1): 1 block/CU -> 256-reg/wave budget. (512,2) capped
// the wave at 128 regs and spilled the 128-reg accumulator to scratch
// (WRITE_SIZE 250MB vs 134MB of Y in round 6).
__global__ __launch_bounds__(512, 1)
void proj_gemm_8ph(const u16* __restrict__ X, const u16* __restrict__ W,
                   const float* __restrict__ bias, u16* __restrict__ Y)
{
    __shared__ __align__(16) u16 As[2][256 * 64];
    __shared__ __align__(16) u16 Bs[2][256 * 64];

    int bx = blockIdx.x;                  // 0..1023
    int wg = (bx & 7) * 128 + (bx >> 3);  // XCD-chunked swizzle (1024 % 8 == 0)
    int bm = wg >> 2;                     // 0..255
    int bn = wg & 3;                      // 0..3

    int tid  = threadIdx.x;
    int lane = tid & 63;
    int wid  = tid >> 6;       // 0..7
    int wm   = wid >> 2;       // 0..1
    int wn   = wid & 3;        // 0..3
    int l15  = lane & 15;
    int l4   = lane >> 4;

    const u16* Xp = X + (size_t)bm * 256 * KDIM;
    const u16* Wp = W + (size_t)bn * 256 * KDIM;

    // staging: lane covers (row_in = tid>>3 in 0..63, col16 = tid&7); the
    // global source col is XOR'd with row so linear LDS dest holds swizzled data
    int srow_in = tid >> 3;
    int scol16  = (tid & 7) ^ (srow_in & 7);

    f32x4 acc[8][4] = {};

    // one half-tile = 128 rows x 64 cols = 2 gload issues (64 rows each)
#define STAGE(lds, gbase, slot, h, kt)                                           \
    {                                                                            \
        const u16* src_ = (gbase) + (size_t)((h) * 128 + srow_in) * KDIM         \
                          + (kt) * 64 + scol16 * 8;                              \
        gload_lds16(src_, &lds[slot][((h) * 128 + wid * 8) * 64]);               \
        gload_lds16(src_ + (size_t)64 * KDIM,                                    \
                    &lds[slot][((h) * 128 + 64 + wid * 8) * 64]);                \
    }

#define READ_AF(slot, mh)                                                        \
    {                                                                            \
        for (int mi = 0; mi < 4; ++mi) {                                         \
            int row = wm * 128 + (mh) * 64 + mi * 16 + l15;                      \
            unsigned o0 = (unsigned)(row * 128 + l4 * 16) ^ (unsigned)((row & 7) << 4); \
            af[mi][0] = *(const bf16x8*)((const char*)As[slot] + o0);            \
            af[mi][1] = *(const bf16x8*)((const char*)As[slot] + (o0 ^ 64u));    \
        }                                                                        \
    }

#define READ_BF(dst, slot, nh)                                                   \
    {                                                                            \
        for (int ni = 0; ni < 2; ++ni) {                                         \
            int row = wn * 64 + (nh) * 32 + ni * 16 + l15;                       \
            unsigned o0 = (unsigned)(row * 128 + l4 * 16) ^ (unsigned)((row & 7) << 4); \
            dst[ni][0] = *(const bf16x8*)((const char*)Bs[slot] + o0);           \
            dst[ni][1] = *(const bf16x8*)((const char*)Bs[slot] + (o0 ^ 64u));   \
        }                                                                        \
    }

#define MFMA_Q(mlo, bb, nlo)                                                     \
    __builtin_amdgcn_s_setprio(1);                                               \
    for (int mi = 0; mi < 4; ++mi)                                               \
        for (int ni = 0; ni < 2; ++ni)                                           \
            for (int kk = 0; kk < 2; ++kk)                                       \
                acc[(mlo) + mi][(nlo) + ni] = __builtin_amdgcn_mfma_f32_16x16x32_bf16( \
                    af[mi][kk], bb[ni][kk], acc[(mlo) + mi][(nlo) + ni], 0, 0, 0); \
    __builtin_amdgcn_s_setprio(0);

    // ---- prologue: kt0 -> slot0 (8 gloads, oldest), A-lo(kt1) -> slot1 (2)
    STAGE(As, Xp, 0, 0, 0);
    STAGE(As, Xp, 0, 1, 0);
    STAGE(Bs, Wp, 0, 0, 0);
    STAGE(Bs, Wp, 0, 1, 0);
    STAGE(As, Xp, 1, 0, 1);
    VMCNT2();                 // kt0's 8 landed; slot1 A-lo may fly
    BARRIER();

    // ---- main loop: 8 iterations x 2 K-tiles
    for (int it = 0; it < 8; ++it) {
        int kt1 = 2 * it + 1;                       // slot1 content this iter
        int kt2 = (2 * it + 2 < 16) ? 2 * it + 2 : 15;  // next slot0 content
        int kt3 = (2 * it + 3 < 16) ? 2 * it + 3 : 15;  // next slot1 content
        bf16x8 af[4][2], b0[2][2], b1[2][2];

        // P1: read slot0 af-lo + b-lo; stage A-hi(kt1)->slot1
        READ_AF(0, 0); READ_BF(b0, 0, 0);
        STAGE(As, Xp, 1, 1, kt1);
        BARRIER(); LGKM0(); SCHED0();
        MFMA_Q(0, b0, 0);
        BARRIER();

        // P2: read b-hi; stage B-lo(kt1)->slot1
        READ_BF(b1, 0, 1);
        STAGE(Bs, Wp, 1, 0, kt1);
        BARRIER(); LGKM0(); SCHED0();
        MFMA_Q(0, b1, 2);
        BARRIER();

        // P3: read af-hi; stage B-hi(kt1)->slot1
        READ_AF(0, 1);
        STAGE(Bs, Wp, 1, 1, kt1);
        BARRIER(); LGKM0(); SCHED0();
        MFMA_Q(4, b1, 2);
        BARRIER();

        // P4: stage A-lo(kt2)->slot0; MFMA from regs; vmcnt(2) BEFORE closing
        //     barrier => slot1 (kt1) fully landed for P5
        STAGE(As, Xp, 0, 0, kt2);
        MFMA_Q(4, b0, 0);
        VMCNT2();
        BARRIER();

        // P5: read slot1 af-lo + b-lo; stage A-hi(kt2)->slot0
        READ_AF(1, 0); READ_BF(b0, 1, 0);
        STAGE(As, Xp, 0, 1, kt2);
        BARRIER(); LGKM0(); SCHED0();
        MFMA_Q(0, b0, 0);
        BARRIER();

        // P6: read b-hi; stage B-lo(kt2)->slot0
        READ_BF(b1, 1, 1);
        STAGE(Bs, Wp, 0, 0, kt2);
        BARRIER(); LGKM0(); SCHED0();
        MFMA_Q(0, b1, 2);
        BARRIER();

        // P7: read af-hi; stage B-hi(kt2)->slot0
        READ_AF(1, 1);
        STAGE(Bs, Wp, 0, 1, kt2);
        BARRIER(); LGKM0(); SCHED0();
        MFMA_Q(4, b1, 2);
        BARRIER();

        // P8: stage A-lo(kt3)->slot1; MFMA from regs; vmcnt(2) => slot0 (kt2)
        //     fully landed for next-iter P1
        STAGE(As, Xp, 1, 0, kt3);
        MFMA_Q(4, b0, 0);
        VMCNT2();
        BARRIER();
    }

    // ---- epilogue: + bias, bf16 store. D-frag: col(N)=l15, rows(M)=l4*4+r
#pragma unroll
    for (int ni = 0; ni < 4; ++ni) {
        int col = bn * 256 + wn * 64 + ni * 16 + l15;
        float bv = bias[col];
#pragma unroll
        for (int mi = 0; mi < 8; ++mi) {
            int row0 = bm * 256 + wm * 128 + mi * 16 + l4 * 4;
#pragma unroll
            for (int r = 0; r < 4; ++r)
                Y[(size_t)(row0 + r) * KDIM + col] = f2bf(acc[mi][ni][r] + bv);
        }
    }
#undef STAGE
#undef READ_AF
#undef READ_BF
#undef MFMA_Q
}

// ---------------- Fallback: fp32 in, convert in-loop (128^2, 2-barrier) -----
__global__ __launch_bounds__(256)
void proj_gemm(const float* __restrict__ X, const float* __restrict__ W,
               const float* __restrict__ bias, u16* __restrict__ Y)
{
    __shared__ u16 As[128 * 64];
    __shared__ u16 Bs[128 * 64];

    int bx = blockIdx.x;
    int wg = (bx & 7) * 512 + (bx >> 3);
    int bm = wg >> 3;
    int bn = wg & 7;

    int tid  = threadIdx.x;
    int lane = tid & 63;
    int wid  = tid >> 6;
    int wrow = (wid >> 1) * 64;
    int wcol = (wid & 1) * 64;
    int l15 = lane & 15;
    int l4  = lane >> 4;

    int srow = tid >> 4;
    int scol = (tid & 15) * 4;

    const float* Xp = X + (size_t)bm * 128 * KDIM;
    const float* Wp = W + (size_t)bn * 128 * KDIM;

    f32x4 acc[4][4] = {};

    for (int k0 = 0; k0 < KDIM; k0 += 64) {
        __syncthreads();
#pragma unroll
        for (int r = 0; r < 8; ++r) {
            int row = r * 16 + srow;
            vfloat4 a = *(const vfloat4*)(Xp + (size_t)row * KDIM + k0 + scol);
            vfloat4 b = *(const vfloat4*)(Wp + (size_t)row * KDIM + k0 + scol);
            ushort4v ap, bp;
#pragma unroll
            for (int j = 0; j < 4; ++j) { ap[j] = f2bf(a[j]); bp[j] = f2bf(b[j]); }
            unsigned off = (unsigned)(row * 128 + scol * 2) ^ (unsigned)((row & 7) << 4);
            *(ushort4v*)((char*)As + off) = ap;
            *(ushort4v*)((char*)Bs + off) = bp;
        }
        __syncthreads();
#pragma unroll
        for (int kk = 0; kk < 2; ++kk) {
            bf16x8 af[4], bfr[4];
#pragma unroll
            for (int mi = 0; mi < 4; ++mi) {
                int row = wrow + mi * 16 + l15;
                unsigned off = (unsigned)(row * 128 + kk * 64 + l4 * 16) ^ (unsigned)((row & 7) << 4);
                af[mi] = *(const bf16x8*)((char*)As + off);
            }
#pragma unroll
            for (int ni = 0; ni < 4; ++ni) {
                int row = wcol + ni * 16 + l15;
                unsigned off = (unsigned)(row * 128 + kk * 64 + l4 * 16) ^ (unsigned)((row & 7) << 4);
                bfr[ni] = *(const bf16x8*)((char*)Bs + off);
            }
#pragma unroll
            for (int mi = 0; mi < 4; ++mi)
#pragma unroll
                for (int ni = 0; ni < 4; ++ni)
                    acc[mi][ni] = __builtin_amdgcn_mfma_f32_16x16x32_bf16(
                        af[mi], bfr[ni], acc[mi][ni], 0, 0, 0);
        }
    }

#pragma unroll
    for (int ni = 0; ni < 4; ++ni) {
        int col = bn * 128 + wcol + ni * 16 + l15;
        float bv = bias[col];
#pragma unroll
        for (int mi = 0; mi < 4; ++mi) {
            int row0 = bm * 128 + wrow + mi * 16 + l4 * 4;
#pragma unroll
            for (int r = 0; r < 4; ++r)
                Y[(size_t)(row0 + r) * KDIM + col] = f2bf(acc[mi][ni][r] + bv);
        }
    }
}

// ---------------- Pass 2: grouped attention ----------------
__global__ __launch_bounds__(256)
void attn_kernel(const u16* __restrict__ Qg, const u16* __restrict__ Kg,
                 const u16* __restrict__ Vg, float* __restrict__ Out)
{
    __shared__ u16 Qs[128 * 64];     // [q][d] swizzled
    __shared__ u16 KVs[64 * 136];    // union: Ks [128][64] swizzled / Vt [64][136]
    __shared__ u16 Ps[128 * 136];    // [q][k], row stride 136

    int g = blockIdx.x >> 4;
    int h = blockIdx.x & 15;

    int tid  = threadIdx.x;
    int lane = tid & 63;
    int wid  = tid >> 6;
    int l15 = lane & 15, l4 = lane >> 4;
    int qbase = wid * 32;

    size_t rowbase = (size_t)g * 128 * 1024 + (size_t)h * 64;

    {
        int r  = tid >> 1;
        int c0 = (tid & 1) * 32;
        const u16* qsrc = Qg + rowbase + (size_t)r * 1024 + c0;
        const u16* ksrc = Kg + rowbase + (size_t)r * 1024 + c0;
#pragma unroll
        for (int i = 0; i < 4; ++i) {
            ushort8v qv = *(const ushort8v*)(qsrc + i * 8);
            ushort8v kv = *(const ushort8v*)(ksrc + i * 8);
            unsigned off = (unsigned)(r * 128 + (c0 + i * 8) * 2) ^ (unsigned)((r & 7) << 4);
            *(ushort8v*)((char*)Qs + off) = qv;
            *(ushort8v*)((char*)KVs + off) = kv;
        }
    }
    __syncthreads();

    f32x4 st[8][2] = {};
#pragma unroll
    for (int kk = 0; kk < 2; ++kk) {
        bf16x8 kf[8];
#pragma unroll
        for (int mi = 0; mi < 8; ++mi) {
            int row = mi * 16 + l15;
            unsigned off = (unsigned)(row * 128 + kk * 64 + l4 * 16) ^ (unsigned)((row & 7) << 4);
            kf[mi] = *(const bf16x8*)((char*)KVs + off);
        }
#pragma unroll
        for (int qi = 0; qi < 2; ++qi) {
            int row = qbase + qi * 16 + l15;
            unsigned off = (unsigned)(row * 128 + kk * 64 + l4 * 16) ^ (unsigned)((row & 7) << 4);
            bf16x8 qf = *(const bf16x8*)((char*)Qs + off);
#pragma unroll
            for (int mi = 0; mi < 8; ++mi)
                st[mi][qi] = __builtin_amdgcn_mfma_f32_16x16x32_bf16(kf[mi], qf, st[mi][qi], 0, 0, 0);
        }
    }
    __syncthreads();

    {
        int r  = tid >> 1;
        int c0 = (tid & 1) * 32;
        const u16* vsrc = Vg + rowbase + (size_t)r * 1024 + c0;
#pragma unroll
        for (int i = 0; i < 4; ++i) {
            ushort8v vv = *(const ushort8v*)(vsrc + i * 8);
#pragma unroll
            for (int e = 0; e < 8; ++e)
                KVs[(c0 + i * 8 + e) * 136 + r] = vv[e];
        }
    }

    const float cexp = 0.125f * 1.44269504088896f;
#pragma unroll
    for (int qi = 0; qi < 2; ++qi) {
        float m = -3.0e38f;
#pragma unroll
        for (int mi = 0; mi < 8; ++mi)
#pragma unroll
            for (int r = 0; r < 4; ++r) m = fmaxf(m, st[mi][qi][r]);
        m = fmaxf(m, __shfl_xor(m, 16));
        m = fmaxf(m, __shfl_xor(m, 32));
        float s = 0.f;
#pragma unroll
        for (int mi = 0; mi < 8; ++mi)
#pragma unroll
            for (int r = 0; r < 4; ++r) {
                float p = exp2f((st[mi][qi][r] - m) * cexp);
                st[mi][qi][r] = p;
                s += p;
            }
        s += __shfl_xor(s, 16);
        s += __shfl_xor(s, 32);
        float inv = 1.0f / s;
        int q = qbase + qi * 16 + l15;
#pragma unroll
        for (int mi = 0; mi < 8; ++mi) {
            ushort4v pp;
#pragma unroll
            for (int r = 0; r < 4; ++r) pp[r] = f2bf(st[mi][qi][r] * inv);
            *(ushort4v*)((char*)Ps + (unsigned)(q * 272 + mi * 32 + l4 * 8)) = pp;
        }
    }
    __syncthreads();

    f32x4 o[2][4] = {};
#pragma unroll
    for (int kk = 0; kk < 4; ++kk) {
        bf16x8 pa[2];
#pragma unroll
        for (int mf = 0; mf < 2; ++mf) {
            int q = qbase + mf * 16 + l15;
            pa[mf] = *(const bf16x8*)((char*)Ps + (unsigned)(q * 272 + kk * 64 + l4 * 16));
        }
#pragma unroll
        for (int nf = 0; nf < 4; ++nf) {
            int d = nf * 16 + l15;
            bf16x8 vb = *(const bf16x8*)((char*)KVs + (unsigned)(d * 272 + kk * 64 + l4 * 16));
#pragma unroll
            for (int mf = 0; mf < 2; ++mf)
                o[mf][nf] = __builtin_amdgcn_mfma_f32_16x16x32_bf16(pa[mf], vb, o[mf][nf], 0, 0, 0);
        }
    }

#pragma unroll
    for (int mf = 0; mf < 2; ++mf)
#pragma unroll
        for (int nf = 0; nf < 4; ++nf) {
            int d  = nf * 16 + l15;
            int q0 = qbase + mf * 16 + l4 * 4;
#pragma unroll
            for (int r = 0; r < 4; ++r)
                Out[(size_t)(g * 128 + q0 + r) * 1024 + h * 64 + d] = o[mf][nf][r];
        }
}

extern "C" void kernel_launch(void* const* d_in, const int* in_sizes, int n_in,
                              void* d_out, int out_size, void* d_ws, size_t ws_size,
                              hipStream_t stream)
{
    const float* Xq = (const float*)d_in[0];
    const float* Xk = (const float*)d_in[1];
    const float* Xv = (const float*)d_in[2];
    const float* Wq = (const float*)d_in[3];
    const float* bq = (const float*)d_in[4];
    const float* Wk = (const float*)d_in[5];
    const float* bk = (const float*)d_in[6];
    const float* Wv = (const float*)d_in[7];
    const float* bv = (const float*)d_in[8];

    const size_t NE = (size_t)NROW * KDIM;       // 67,108,864
    const size_t WE = (size_t)KDIM * KDIM;       // 1,048,576

    u16* Qw = (u16*)d_ws;
    u16* Kw = Qw + NE;
    u16* Vw = Kw + NE;

    size_t need = NE * 2 * 3 + NE * 2 + WE * 2 * 3;  // QKV + X-stage + 3 W

    if (ws_size >= need) {
        u16* Xb  = Vw + NE;          // shared X staging buffer (reused 3x)
        u16* Wb0 = Xb + NE;
        u16* Wb1 = Wb0 + WE;
        u16* Wb2 = Wb1 + WE;

        cvt_f32_bf16<<<dim3(512),  dim3(256), 0, stream>>>(Wq, Wb0, (unsigned)(WE / 8));
        cvt_f32_bf16<<<dim3(512),  dim3(256), 0, stream>>>(Wk, Wb1, (unsigned)(WE / 8));
        cvt_f32_bf16<<<dim3(512),  dim3(256), 0, stream>>>(Wv, Wb2, (unsigned)(WE / 8));

        cvt_f32_bf16<<<dim3(2048), dim3(256), 0, stream>>>(Xq, Xb, (unsigned)(NE / 8));
        proj_gemm_8ph<<<dim3(1024), dim3(512), 0, stream>>>(Xb, Wb0, bq, Qw);
        cvt_f32_bf16<<<dim3(2048), dim3(256), 0, stream>>>(Xk, Xb, (unsigned)(NE / 8));
        proj_gemm_8ph<<<dim3(1024), dim3(512), 0, stream>>>(Xb, Wb1, bk, Kw);
        cvt_f32_bf16<<<dim3(2048), dim3(256), 0, stream>>>(Xv, Xb, (unsigned)(NE / 8));
        proj_gemm_8ph<<<dim3(1024), dim3(512), 0, stream>>>(Xb, Wb2, bv, Vw);
    } else {
        proj_gemm<<<dim3(4096), dim3(256), 0, stream>>>(Xq, Wq, bq, Qw);
        proj_gemm<<<dim3(4096), dim3(256), 0, stream>>>(Xk, Wk, bk, Kw);
        proj_gemm<<<dim3(4096), dim3(256), 0, stream>>>(Xv, Wv, bv, Vw);
    }

    attn_kernel<<<dim3(512 * 16), dim3(256), 0, stream>>>(Qw, Kw, Vw, (float*)d_out);
}

// Round 8
// 926.777 us; speedup vs baseline: 1.6289x; 1.0006x over previous
//
#include <hip/hip_runtime.h>
#include <hip/hip_bf16.h>

typedef unsigned short u16;
typedef __attribute__((ext_vector_type(8))) short bf16x8;
typedef __attribute__((ext_vector_type(4))) float f32x4;
typedef __attribute__((ext_vector_type(4))) float vfloat4;
typedef __attribute__((ext_vector_type(4))) unsigned short ushort4v;
typedef __attribute__((ext_vector_type(8))) unsigned short ushort8v;

#define DEV __device__ __forceinline__
#define AS1 __attribute__((address_space(1)))
#define AS3 __attribute__((address_space(3)))

#define BARRIER()  __builtin_amdgcn_s_barrier()
#define LGKM0()    asm volatile("s_waitcnt lgkmcnt(0)" ::: "memory")
#define VMCNT2()   asm volatile("s_waitcnt vmcnt(2)" ::: "memory")
#define SCHED0()   __builtin_amdgcn_sched_barrier(0)

DEV u16 f2bf(float f) {
    union { float f; unsigned u; } v; v.f = f;
    unsigned r = v.u + 0x7FFFu + ((v.u >> 16) & 1u);
    return (u16)(r >> 16);
}

DEV void gload_lds16(const void* g, void* l) {
    __builtin_amdgcn_global_load_lds((const AS1 unsigned int*)g,
                                     (AS3 unsigned int*)l, 16, 0, 0);
}

static constexpr int KDIM = 1024;   // embed
static constexpr int NROW = 65536;  // B*S

// ---------------- fp32 -> bf16 convert (memory-bound) ----------------
__global__ __launch_bounds__(256)
void cvt_f32_bf16(const float* __restrict__ src, u16* __restrict__ dst, unsigned n8)
{
    unsigned stride = gridDim.x * blockDim.x;
    for (unsigned i = blockIdx.x * blockDim.x + threadIdx.x; i < n8; i += stride) {
        size_t base = (size_t)i * 8;
        vfloat4 a = *(const vfloat4*)(src + base);
        vfloat4 b = *(const vfloat4*)(src + base + 4);
        ushort8v o;
#pragma unroll
        for (int j = 0; j < 4; ++j) { o[j] = f2bf(a[j]); o[j + 4] = f2bf(b[j]); }
        *(ushort8v*)(dst + base) = o;
    }
}

// ---------------- 8-phase 256^2 bf16 GEMM (m201 port) ------------------------
// Y = Xb @ Wb^T + b. All bf16 in. BM=BN=256, BK=64, 16 K-tiles, 8 waves (2Mx4N),
// per-wave C 128x64 (acc[8][4]). Both A,B staged via global_load_lds with
// pre-swizzled source (rule #21); fixed slot pairing. 8 phases / 2 K-tiles;
// counted vmcnt(2) only at P4/P8 before the closing barrier.
// ALL macro loops carry _Pragma("unroll"): a rolled loop would runtime-index
// acc/af ext_vector arrays -> scratch (rule #20) -> the 116MB WRITE excess
// and latency-bound phases seen in rounds 5-7.
__global__ __launch_bounds__(512)
__attribute__((amdgpu_waves_per_eu(1, 2)))
void proj_gemm_8ph(const u16* __restrict__ X, const u16* __restrict__ W,
                   const float* __restrict__ bias, u16* __restrict__ Y)
{
    __shared__ __align__(16) u16 As[2][256 * 64];
    __shared__ __align__(16) u16 Bs[2][256 * 64];

    int bx = blockIdx.x;                  // 0..1023
    int wg = (bx & 7) * 128 + (bx >> 3);  // XCD-chunked swizzle (1024 % 8 == 0)
    int bm = wg >> 2;                     // 0..255
    int bn = wg & 3;                      // 0..3

    int tid  = threadIdx.x;
    int lane = tid & 63;
    int wid  = tid >> 6;       // 0..7
    int wm   = wid >> 2;       // 0..1
    int wn   = wid & 3;        // 0..3
    int l15  = lane & 15;
    int l4   = lane >> 4;

    const u16* Xp = X + (size_t)bm * 256 * KDIM;
    const u16* Wp = W + (size_t)bn * 256 * KDIM;

    // staging: lane covers (row_in = tid>>3 in 0..63, col16 = tid&7); the
    // global source col is XOR'd with row so linear LDS dest holds swizzled data
    int srow_in = tid >> 3;
    int scol16  = (tid & 7) ^ (srow_in & 7);

    f32x4 acc[8][4] = {};

    // one half-tile = 128 rows x 64 cols = 2 gload issues (64 rows each)
#define STAGE(lds, gbase, slot, h, kt)                                           \
    {                                                                            \
        const u16* src_ = (gbase) + (size_t)((h) * 128 + srow_in) * KDIM         \
                          + (kt) * 64 + scol16 * 8;                              \
        gload_lds16(src_, &lds[slot][((h) * 128 + wid * 8) * 64]);               \
        gload_lds16(src_ + (size_t)64 * KDIM,                                    \
                    &lds[slot][((h) * 128 + 64 + wid * 8) * 64]);                \
    }

#define READ_AF(slot, mh)                                                        \
    {                                                                            \
        _Pragma("unroll")                                                        \
        for (int mi = 0; mi < 4; ++mi) {                                         \
            int row = wm * 128 + (mh) * 64 + mi * 16 + l15;                      \
            unsigned o0 = (unsigned)(row * 128 + l4 * 16) ^ (unsigned)((row & 7) << 4); \
            af[mi][0] = *(const bf16x8*)((const char*)As[slot] + o0);            \
            af[mi][1] = *(const bf16x8*)((const char*)As[slot] + (o0 ^ 64u));    \
        }                                                                        \
    }

#define READ_BF(dst, slot, nh)                                                   \
    {                                                                            \
        _Pragma("unroll")                                                        \
        for (int ni = 0; ni < 2; ++ni) {                                         \
            int row = wn * 64 + (nh) * 32 + ni * 16 + l15;                       \
            unsigned o0 = (unsigned)(row * 128 + l4 * 16) ^ (unsigned)((row & 7) << 4); \
            dst[ni][0] = *(const bf16x8*)((const char*)Bs[slot] + o0);           \
            dst[ni][1] = *(const bf16x8*)((const char*)Bs[slot] + (o0 ^ 64u));   \
        }                                                                        \
    }

#define MFMA_Q(mlo, bb, nlo)                                                     \
    __builtin_amdgcn_s_setprio(1);                                               \
    _Pragma("unroll")                                                            \
    for (int mi = 0; mi < 4; ++mi) {                                             \
        _Pragma("unroll")                                                        \
        for (int ni = 0; ni < 2; ++ni) {                                         \
            _Pragma("unroll")                                                    \
            for (int kk = 0; kk < 2; ++kk)                                       \
                acc[(mlo) + mi][(nlo) + ni] = __builtin_amdgcn_mfma_f32_16x16x32_bf16( \
                    af[mi][kk], bb[ni][kk], acc[(mlo) + mi][(nlo) + ni], 0, 0, 0); \
        }                                                                        \
    }                                                                            \
    __builtin_amdgcn_s_setprio(0);

    // ---- prologue: kt0 -> slot0 (8 gloads, oldest), A-lo(kt1) -> slot1 (2)
    STAGE(As, Xp, 0, 0, 0);
    STAGE(As, Xp, 0, 1, 0);
    STAGE(Bs, Wp, 0, 0, 0);
    STAGE(Bs, Wp, 0, 1, 0);
    STAGE(As, Xp, 1, 0, 1);
    VMCNT2();                 // kt0's 8 landed; slot1 A-lo may fly
    BARRIER();

    // ---- main loop: 8 iterations x 2 K-tiles
    for (int it = 0; it < 8; ++it) {
        int kt1 = 2 * it + 1;                       // slot1 content this iter
        int kt2 = (2 * it + 2 < 16) ? 2 * it + 2 : 15;  // next slot0 content
        int kt3 = (2 * it + 3 < 16) ? 2 * it + 3 : 15;  // next slot1 content
        bf16x8 af[4][2], b0[2][2], b1[2][2];

        // P1: read slot0 af-lo + b-lo; stage A-hi(kt1)->slot1
        READ_AF(0, 0); READ_BF(b0, 0, 0);
        STAGE(As, Xp, 1, 1, kt1);
        BARRIER(); LGKM0(); SCHED0();
        MFMA_Q(0, b0, 0);
        BARRIER();

        // P2: read b-hi; stage B-lo(kt1)->slot1
        READ_BF(b1, 0, 1);
        STAGE(Bs, Wp, 1, 0, kt1);
        BARRIER(); LGKM0(); SCHED0();
        MFMA_Q(0, b1, 2);
        BARRIER();

        // P3: read af-hi; stage B-hi(kt1)->slot1
        READ_AF(0, 1);
        STAGE(Bs, Wp, 1, 1, kt1);
        BARRIER(); LGKM0(); SCHED0();
        MFMA_Q(4, b1, 2);
        BARRIER();

        // P4: stage A-lo(kt2)->slot0; MFMA from regs; vmcnt(2) BEFORE closing
        //     barrier => slot1 (kt1) fully landed for P5
        STAGE(As, Xp, 0, 0, kt2);
        MFMA_Q(4, b0, 0);
        VMCNT2();
        BARRIER();

        // P5: read slot1 af-lo + b-lo; stage A-hi(kt2)->slot0
        READ_AF(1, 0); READ_BF(b0, 1, 0);
        STAGE(As, Xp, 0, 1, kt2);
        BARRIER(); LGKM0(); SCHED0();
        MFMA_Q(0, b0, 0);
        BARRIER();

        // P6: read b-hi; stage B-lo(kt2)->slot0
        READ_BF(b1, 1, 1);
        STAGE(Bs, Wp, 0, 0, kt2);
        BARRIER(); LGKM0(); SCHED0();
        MFMA_Q(0, b1, 2);
        BARRIER();

        // P7: read af-hi; stage B-hi(kt2)->slot0
        READ_AF(1, 1);
        STAGE(Bs, Wp, 0, 1, kt2);
        BARRIER(); LGKM0(); SCHED0();
        MFMA_Q(4, b1, 2);
        BARRIER();

        // P8: stage A-lo(kt3)->slot1; MFMA from regs; vmcnt(2) => slot0 (kt2)
        //     fully landed for next-iter P1
        STAGE(As, Xp, 1, 0, kt3);
        MFMA_Q(4, b0, 0);
        VMCNT2();
        BARRIER();
    }

    // ---- epilogue: + bias, bf16 store. D-frag: col(N)=l15, rows(M)=l4*4+r
#pragma unroll
    for (int ni = 0; ni < 4; ++ni) {
        int col = bn * 256 + wn * 64 + ni * 16 + l15;
        float bv = bias[col];
#pragma unroll
        for (int mi = 0; mi < 8; ++mi) {
            int row0 = bm * 256 + wm * 128 + mi * 16 + l4 * 4;
#pragma unroll
            for (int r = 0; r < 4; ++r)
                Y[(size_t)(row0 + r) * KDIM + col] = f2bf(acc[mi][ni][r] + bv);
        }
    }
#undef STAGE
#undef READ_AF
#undef READ_BF
#undef MFMA_Q
}

// ---------------- Fallback: fp32 in, convert in-loop (128^2, 2-barrier) -----
__global__ __launch_bounds__(256)
void proj_gemm(const float* __restrict__ X, const float* __restrict__ W,
               const float* __restrict__ bias, u16* __restrict__ Y)
{
    __shared__ u16 As[128 * 64];
    __shared__ u16 Bs[128 * 64];

    int bx = blockIdx.x;
    int wg = (bx & 7) * 512 + (bx >> 3);
    int bm = wg >> 3;
    int bn = wg & 7;

    int tid  = threadIdx.x;
    int lane = tid & 63;
    int wid  = tid >> 6;
    int wrow = (wid >> 1) * 64;
    int wcol = (wid & 1) * 64;
    int l15 = lane & 15;
    int l4  = lane >> 4;

    int srow = tid >> 4;
    int scol = (tid & 15) * 4;

    const float* Xp = X + (size_t)bm * 128 * KDIM;
    const float* Wp = W + (size_t)bn * 128 * KDIM;

    f32x4 acc[4][4] = {};

    for (int k0 = 0; k0 < KDIM; k0 += 64) {
        __syncthreads();
#pragma unroll
        for (int r = 0; r < 8; ++r) {
            int row = r * 16 + srow;
            vfloat4 a = *(const vfloat4*)(Xp + (size_t)row * KDIM + k0 + scol);
            vfloat4 b = *(const vfloat4*)(Wp + (size_t)row * KDIM + k0 + scol);
            ushort4v ap, bp;
#pragma unroll
            for (int j = 0; j < 4; ++j) { ap[j] = f2bf(a[j]); bp[j] = f2bf(b[j]); }
            unsigned off = (unsigned)(row * 128 + scol * 2) ^ (unsigned)((row & 7) << 4);
            *(ushort4v*)((char*)As + off) = ap;
            *(ushort4v*)((char*)Bs + off) = bp;
        }
        __syncthreads();
#pragma unroll
        for (int kk = 0; kk < 2; ++kk) {
            bf16x8 af[4], bfr[4];
#pragma unroll
            for (int mi = 0; mi < 4; ++mi) {
                int row = wrow + mi * 16 + l15;
                unsigned off = (unsigned)(row * 128 + kk * 64 + l4 * 16) ^ (unsigned)((row & 7) << 4);
                af[mi] = *(const bf16x8*)((char*)As + off);
            }
#pragma unroll
            for (int ni = 0; ni < 4; ++ni) {
                int row = wcol + ni * 16 + l15;
                unsigned off = (unsigned)(row * 128 + kk * 64 + l4 * 16) ^ (unsigned)((row & 7) << 4);
                bfr[ni] = *(const bf16x8*)((char*)Bs + off);
            }
#pragma unroll
            for (int mi = 0; mi < 4; ++mi)
#pragma unroll
                for (int ni = 0; ni < 4; ++ni)
                    acc[mi][ni] = __builtin_amdgcn_mfma_f32_16x16x32_bf16(
                        af[mi], bfr[ni], acc[mi][ni], 0, 0, 0);
        }
    }

#pragma unroll
    for (int ni = 0; ni < 4; ++ni) {
        int col = bn * 128 + wcol + ni * 16 + l15;
        float bv = bias[col];
#pragma unroll
        for (int mi = 0; mi < 4; ++mi) {
            int row0 = bm * 128 + wrow + mi * 16 + l4 * 4;
#pragma unroll
            for (int r = 0; r < 4; ++r)
                Y[(size_t)(row0 + r) * KDIM + col] = f2bf(acc[mi][ni][r] + bv);
        }
    }
}

// ---------------- Pass 2: grouped attention ----------------
__global__ __launch_bounds__(256)
void attn_kernel(const u16* __restrict__ Qg, const u16* __restrict__ Kg,
                 const u16* __restrict__ Vg, float* __restrict__ Out)
{
    __shared__ u16 Qs[128 * 64];     // [q][d] swizzled
    __shared__ u16 KVs[64 * 136];    // union: Ks [128][64] swizzled / Vt [64][136]
    __shared__ u16 Ps[128 * 136];    // [q][k], row stride 136

    int g = blockIdx.x >> 4;
    int h = blockIdx.x & 15;

    int tid  = threadIdx.x;
    int lane = tid & 63;
    int wid  = tid >> 6;
    int l15 = lane & 15, l4 = lane >> 4;
    int qbase = wid * 32;

    size_t rowbase = (size_t)g * 128 * 1024 + (size_t)h * 64;

    {
        int r  = tid >> 1;
        int c0 = (tid & 1) * 32;
        const u16* qsrc = Qg + rowbase + (size_t)r * 1024 + c0;
        const u16* ksrc = Kg + rowbase + (size_t)r * 1024 + c0;
#pragma unroll
        for (int i = 0; i < 4; ++i) {
            ushort8v qv = *(const ushort8v*)(qsrc + i * 8);
            ushort8v kv = *(const ushort8v*)(ksrc + i * 8);
            unsigned off = (unsigned)(r * 128 + (c0 + i * 8) * 2) ^ (unsigned)((r & 7) << 4);
            *(ushort8v*)((char*)Qs + off) = qv;
            *(ushort8v*)((char*)KVs + off) = kv;
        }
    }
    __syncthreads();

    f32x4 st[8][2] = {};
#pragma unroll
    for (int kk = 0; kk < 2; ++kk) {
        bf16x8 kf[8];
#pragma unroll
        for (int mi = 0; mi < 8; ++mi) {
            int row = mi * 16 + l15;
            unsigned off = (unsigned)(row * 128 + kk * 64 + l4 * 16) ^ (unsigned)((row & 7) << 4);
            kf[mi] = *(const bf16x8*)((char*)KVs + off);
        }
#pragma unroll
        for (int qi = 0; qi < 2; ++qi) {
            int row = qbase + qi * 16 + l15;
            unsigned off = (unsigned)(row * 128 + kk * 64 + l4 * 16) ^ (unsigned)((row & 7) << 4);
            bf16x8 qf = *(const bf16x8*)((char*)Qs + off);
#pragma unroll
            for (int mi = 0; mi < 8; ++mi)
                st[mi][qi] = __builtin_amdgcn_mfma_f32_16x16x32_bf16(kf[mi], qf, st[mi][qi], 0, 0, 0);
        }
    }
    __syncthreads();

    {
        int r  = tid >> 1;
        int c0 = (tid & 1) * 32;
        const u16* vsrc = Vg + rowbase + (size_t)r * 1024 + c0;
#pragma unroll
        for (int i = 0; i < 4; ++i) {
            ushort8v vv = *(const ushort8v*)(vsrc + i * 8);
#pragma unroll
            for (int e = 0; e < 8; ++e)
                KVs[(c0 + i * 8 + e) * 136 + r] = vv[e];
        }
    }

    const float cexp = 0.125f * 1.44269504088896f;
#pragma unroll
    for (int qi = 0; qi < 2; ++qi) {
        float m = -3.0e38f;
#pragma unroll
        for (int mi = 0; mi < 8; ++mi)
#pragma unroll
            for (int r = 0; r < 4; ++r) m = fmaxf(m, st[mi][qi][r]);
        m = fmaxf(m, __shfl_xor(m, 16));
        m = fmaxf(m, __shfl_xor(m, 32));
        float s = 0.f;
#pragma unroll
        for (int mi = 0; mi < 8; ++mi)
#pragma unroll
            for (int r = 0; r < 4; ++r) {
                float p = exp2f((st[mi][qi][r] - m) * cexp);
                st[mi][qi][r] = p;
                s += p;
            }
        s += __shfl_xor(s, 16);
        s += __shfl_xor(s, 32);
        float inv = 1.0f / s;
        int q = qbase + qi * 16 + l15;
#pragma unroll
        for (int mi = 0; mi < 8; ++mi) {
            ushort4v pp;
#pragma unroll
            for (int r = 0; r < 4; ++r) pp[r] = f2bf(st[mi][qi][r] * inv);
            *(ushort4v*)((char*)Ps + (unsigned)(q * 272 + mi * 32 + l4 * 8)) = pp;
        }
    }
    __syncthreads();

    f32x4 o[2][4] = {};
#pragma unroll
    for (int kk = 0; kk < 4; ++kk) {
        bf16x8 pa[2];
#pragma unroll
        for (int mf = 0; mf < 2; ++mf) {
            int q = qbase + mf * 16 + l15;
            pa[mf] = *(const bf16x8*)((char*)Ps + (unsigned)(q * 272 + kk * 64 + l4 * 16));
        }
#pragma unroll
        for (int nf = 0; nf < 4; ++nf) {
            int d = nf * 16 + l15;
            bf16x8 vb = *(const bf16x8*)((char*)KVs + (unsigned)(d * 272 + kk * 64 + l4 * 16));
#pragma unroll
            for (int mf = 0; mf < 2; ++mf)
                o[mf][nf] = __builtin_amdgcn_mfma_f32_16x16x32_bf16(pa[mf], vb, o[mf][nf], 0, 0, 0);
        }
    }

#pragma unroll
    for (int mf = 0; mf < 2; ++mf)
#pragma unroll
        for (int nf = 0; nf < 4; ++nf) {
            int d  = nf * 16 + l15;
            int q0 = qbase + mf * 16 + l4 * 4;
#pragma unroll
            for (int r = 0; r < 4; ++r)
                Out[(size_t)(g * 128 + q0 + r) * 1024 + h * 64 + d] = o[mf][nf][r];
        }
}

extern "C" void kernel_launch(void* const* d_in, const int* in_sizes, int n_in,
                              void* d_out, int out_size, void* d_ws, size_t ws_size,
                              hipStream_t stream)
{
    const float* Xq = (const float*)d_in[0];
    const float* Xk = (const float*)d_in[1];
    const float* Xv = (const float*)d_in[2];
    const float* Wq = (const float*)d_in[3];
    const float* bq = (const float*)d_in[4];
    const float* Wk = (const float*)d_in[5];
    const float* bk = (const float*)d_in[6];
    const float* Wv = (const float*)d_in[7];
    const float* bv = (const float*)d_in[8];

    const size_t NE = (size_t)NROW * KDIM;       // 67,108,864
    const size_t WE = (size_t)KDIM * KDIM;       // 1,048,576

    u16* Qw = (u16*)d_ws;
    u16* Kw = Qw + NE;
    u16* Vw = Kw + NE;

    size_t need = NE * 2 * 3 + NE * 2 + WE * 2 * 3;  // QKV + X-stage + 3 W

    if (ws_size >= need) {
        u16* Xb  = Vw + NE;          // shared X staging buffer (reused 3x)
        u16* Wb0 = Xb + NE;
        u16* Wb1 = Wb0 + WE;
        u16* Wb2 = Wb1 + WE;

        cvt_f32_bf16<<<dim3(512),  dim3(256), 0, stream>>>(Wq, Wb0, (unsigned)(WE / 8));
        cvt_f32_bf16<<<dim3(512),  dim3(256), 0, stream>>>(Wk, Wb1, (unsigned)(WE / 8));
        cvt_f32_bf16<<<dim3(512),  dim3(256), 0, stream>>>(Wv, Wb2, (unsigned)(WE / 8));

        cvt_f32_bf16<<<dim3(2048), dim3(256), 0, stream>>>(Xq, Xb, (unsigned)(NE / 8));
        proj_gemm_8ph<<<dim3(1024), dim3(512), 0, stream>>>(Xb, Wb0, bq, Qw);
        cvt_f32_bf16<<<dim3(2048), dim3(256), 0, stream>>>(Xk, Xb, (unsigned)(NE / 8));
        proj_gemm_8ph<<<dim3(1024), dim3(512), 0, stream>>>(Xb, Wb1, bk, Kw);
        cvt_f32_bf16<<<dim3(2048), dim3(256), 0, stream>>>(Xv, Xb, (unsigned)(NE / 8));
        proj_gemm_8ph<<<dim3(1024), dim3(512), 0, stream>>>(Xb, Wb2, bv, Vw);
    } else {
        proj_gemm<<<dim3(4096), dim3(256), 0, stream>>>(Xq, Wq, bq, Qw);
        proj_gemm<<<dim3(4096), dim3(256), 0, stream>>>(Xk, Wk, bk, Kw);
        proj_gemm<<<dim3(4096), dim3(256), 0, stream>>>(Xv, Wv, bv, Vw);
    }

    attn_kernel<<<dim3(512 * 16), dim3(256), 0, stream>>>(Qw, Kw, Vw, (float*)d_out);
}